// Round 15
// baseline (425.613 us; speedup 1.0000x reference)
//
#include <hip/hip_runtime.h>

typedef unsigned int u32;
typedef __fp16 half2_t __attribute__((ext_vector_type(2)));
typedef __fp16 half8_t __attribute__((ext_vector_type(8)));
typedef float  f32x4   __attribute__((ext_vector_type(4)));
typedef int    i32x4   __attribute__((ext_vector_type(4)));

#define DIN 128
#define DH  128
#define SEQL 512
#define NBATCH 256
#define NC  512          // 4*DH fused gate columns
#define TC  32           // timesteps per chunk (2 elements -> smaller chunks)
#define NCHUNK (SEQL/TC) // 16

// LDS: xgT e0 @ {0, 32768}, e1 @ {65536, 98304} ([col][64 B of t] swizzled)
#define HOFF 131072      // h i8 dbufs: e0 @ HOFF (2x128B), e1 @ HOFF+256
#define HF2  (131072 + 512)   // final f16 h: e0 @ +512, e1 @ +768
#define LDS_TOTAL (131072 + 1024)

__device__ __forceinline__ u32 pk2(float a, float b) {
  half2_t h = __builtin_amdgcn_cvt_pkrtz(a, b);
  return __builtin_bit_cast(u32, h);
}

__device__ __forceinline__ float fexp2(float x) {
#if defined(__has_builtin) && __has_builtin(__builtin_amdgcn_exp2f)
  return __builtin_amdgcn_exp2f(x);
#else
  return __builtin_exp2f(x);
#endif
}

// 64-B-row XOR swizzle: 16B-granule position = (t16 ^ ((col ^ col>>2)&3))
__device__ __forceinline__ u32 swz(int col) {
  return ((u32)((col ^ (col >> 2)) & 3)) << 4;
}

// raw step barrier: publish LDS writes (lgkm only), keep global loads in flight
__device__ __forceinline__ void step_barrier() {
  asm volatile("s_waitcnt lgkmcnt(0)" ::: "memory");
  __builtin_amdgcn_s_barrier();
  asm volatile("" ::: "memory");
}

#define MF(A, B, C) __builtin_amdgcn_mfma_f32_16x16x32_f16( \
    __builtin_bit_cast(half8_t, A), __builtin_bit_cast(half8_t, B), C, 0, 0, 0)
#define MFI8(A, B, C) __builtin_amdgcn_mfma_i32_16x16x64_i8( \
    __builtin_bit_cast(i32x4, A), __builtin_bit_cast(i32x4, B), C, 0, 0, 0)

// Pack fused x-projection weights (f16 pairs, pre-scaled by exp2 constants)
__global__ void pack_w(const float* __restrict__ x2i, const float* __restrict__ x2f,
                       const float* __restrict__ x2g, const float* __restrict__ x2o,
                       u32* __restrict__ wxT) {
  int idx = blockIdx.x * blockDim.x + threadIdx.x;   // 0..32767
  if (idx >= NC * 64) return;
  int j = idx >> 6, kk = idx & 63;
  int g = j >> 7, jjj = j & 127;
  const float* wx = (g == 0) ? x2i : (g == 1) ? x2f : (g == 2) ? x2g : x2o;
  float s = (g == 2) ? -2.885390082f : -1.442695041f;
  wxT[idx] = pk2(s * wx[(2*kk)*DH + jjj], s * wx[(2*kk+1)*DH + jjj]);
}

// Quantize recurrence weights to i8 (per-column scale; dequant folds exp2 const)
__global__ void pack_whi8(const float* __restrict__ h2i, const float* __restrict__ h2f,
                          const float* __restrict__ h2g, const float* __restrict__ h2o,
                          u32* __restrict__ whI, float* __restrict__ dqs) {
  int j = blockIdx.x * blockDim.x + threadIdx.x;   // 0..511 fused col
  if (j >= NC) return;
  int g = j >> 7, jj = j & 127;
  const float* wh = (g == 0) ? h2i : (g == 1) ? h2f : (g == 2) ? h2g : h2o;
  float amax = 1e-20f;
  for (int k = 0; k < DH; ++k) amax = fmaxf(amax, fabsf(wh[k*DH + jj]));
  float s = 127.f / amax;
  for (int kk = 0; kk < 32; ++kk) {
    u32 wword = 0;
#pragma unroll
    for (int t = 0; t < 4; ++t) {
      int q = (int)__builtin_rintf(wh[(4*kk + t)*DH + jj] * s);
      wword |= ((u32)(q & 0xFF)) << (8 * t);
    }
    whI[j*32 + kk] = wword;
  }
  dqs[j] = (amax / 16129.f) * ((g == 2) ? -2.885390082f : -1.442695041f);
}

// Each block owns TWO batch elements (in-wave ILP: e1's chain issues under
// e0's latencies). Weights shared; per-element state: xgT dbuf, h dbuf, c.
__global__ __launch_bounds__(512, 2)
void lstm_fused(
    const float* __restrict__ x, const u32* __restrict__ wxT,
    const u32* __restrict__ whI, const float* __restrict__ dqs,
    const float* __restrict__ w_out, float* __restrict__ out) {
  extern __shared__ char lds[];

  const int tid = threadIdx.x;
  const int b0  = blockIdx.x * 2, b1 = b0 + 1;
  const int l   = tid & 63, wv = tid >> 6;
  const int kg  = l >> 4, r15 = l & 15;
  const int j   = wv * 16 + r15;   // hidden index this lane owns

  // i8 recurrence B-frags (shared by both elements)
  uint4 bi8[4][2];
#pragma unroll
  for (int g = 0; g < 4; ++g) {
    const uint4* wp = (const uint4*)(whI + (g * DH + j) * 32);
    bi8[g][0] = wp[kg];
    bi8[g][1] = wp[4 + kg];
  }
  const float dqo = dqs[kg * DH + j];
  const float cA = (kg == 2) ? 2.f : 1.f;
  const float cB = (kg == 2) ? -1.f : 0.f;
  // Phase-A B-frags (shared, persistent)
  uint4 bfA[4][4];
#pragma unroll
  for (int nt = 0; nt < 4; ++nt) {
    int n = wv * 64 + nt * 16 + r15;
#pragma unroll
    for (int ko = 0; ko < 4; ++ko)
      bfA[nt][ko] = *(const uint4*)(wxT + n*64 + ko*16 + kg*4);
  }

  if (tid < 128) ((u32*)(lds + HOFF))[tid] = 0u;   // zero all 4 h buffers
  float c0 = 0.f, c1 = 0.f, lasth0 = 0.f, lasth1 = 0.f;
  u32 rdh0 = HOFF,       wrh0 = HOFF + 128;
  u32 rdh1 = HOFF + 256, wrh1 = HOFF + 384;
  const float* xb0 = x + (size_t)b0 * SEQL * DIN;
  const float* xb1 = x + (size_t)b1 * SEQL * DIN;
  const f32x4 Z  = {0.f, 0.f, 0.f, 0.f};
  const i32x4 ZI = {0, 0, 0, 0};
  __syncthreads();

  // ---- standalone phase A for chunk 0, both elements ----
#pragma unroll 1
  for (int e = 0; e < 2; ++e) {
    const float* xbe = e ? xb1 : xb0;
    char* dst = lds + e * 65536;      // buffer 0 of element e
#pragma unroll 1
    for (int tt = 0; tt < 2; ++tt) {
      uint4 afr0[4];
#pragma unroll
      for (int ko = 0; ko < 4; ++ko) {
        const float4* xp = (const float4*)(xbe + (size_t)(tt*16 + r15)*DIN + ko*32 + kg*8);
        float4 v0 = xp[0], v1 = xp[1];
        afr0[ko].x = pk2(v0.x, v0.y); afr0[ko].y = pk2(v0.z, v0.w);
        afr0[ko].z = pk2(v1.x, v1.y); afr0[ko].w = pk2(v1.z, v1.w);
      }
#pragma unroll
      for (int nt = 0; nt < 4; ++nt) {
        int n = wv * 64 + nt * 16 + r15;
        f32x4 acc = MF(afr0[0], bfA[nt][0], Z);
        acc = MF(afr0[1], bfA[nt][1], acc);
        acc = MF(afr0[2], bfA[nt][2], acc);
        acc = MF(afr0[3], bfA[nt][3], acc);
        int t0 = tt*16 + kg*4;
        u32 off = (u32)(n*64 + ((t0*2) ^ swz(n)));
        uint2 pw; pw.x = pk2(acc[0], acc[1]); pw.y = pk2(acc[2], acc[3]);
        *(uint2*)(dst + off) = pw;
      }
    }
  }
  __syncthreads();

  int cur = 0;
#pragma unroll 1
  for (int ch = 0; ch < NCHUNK; ++ch) {
    char* xgC0 = lds + cur * 32768;
    char* xgC1 = lds + 65536 + cur * 32768;
    char* xgN0 = lds + (cur ^ 1) * 32768;
    char* xgN1 = lds + 65536 + (cur ^ 1) * 32768;
    const bool doA = (ch + 1 < NCHUNK);
    float4 lv[8];          // staged x loads (reused e0 then e1)
    uint4  afrA[4], afrB[4];
    f32x4  aaccA, aaccB;

#pragma unroll 1
    for (int m = 0; m < 4; ++m) {
      const int tt = m >> 1;
      const int cg = kg * DH + j;   // own-gate column
      half8_t xh0 = __builtin_bit_cast(half8_t,
          *(const uint4*)(xgC0 + cg*64 + ((m*16) ^ swz(cg))));
      half8_t xh1 = __builtin_bit_cast(half8_t,
          *(const uint4*)(xgC1 + cg*64 + ((m*16) ^ swz(cg))));
#pragma unroll
      for (int s8 = 0; s8 < 8; ++s8) {
        // ---- interleaved phase A (chunk ch+1, both elements) ----
        if (doA) {
          if ((m & 1) == 0) {
            if (s8 == 0) {
              const float* xr = xb0 + (size_t)((ch+1)*TC + tt*16 + r15)*DIN + kg*8;
#pragma unroll
              for (int ko = 0; ko < 4; ++ko) {
                const float4* xp = (const float4*)(xr + ko*32);
                lv[2*ko]   = xp[0];
                lv[2*ko+1] = xp[1];
              }
            }
            if (s8 == 2) {
#pragma unroll
              for (int ko = 0; ko < 2; ++ko) {
                float4 v0 = lv[2*ko], v1 = lv[2*ko+1];
                afrA[ko].x = pk2(v0.x, v0.y); afrA[ko].y = pk2(v0.z, v0.w);
                afrA[ko].z = pk2(v1.x, v1.y); afrA[ko].w = pk2(v1.z, v1.w);
              }
            }
            if (s8 == 3) {
#pragma unroll
              for (int ko = 2; ko < 4; ++ko) {
                float4 v0 = lv[2*ko], v1 = lv[2*ko+1];
                afrA[ko].x = pk2(v0.x, v0.y); afrA[ko].y = pk2(v0.z, v0.w);
                afrA[ko].z = pk2(v1.x, v1.y); afrA[ko].w = pk2(v1.z, v1.w);
              }
            }
            if (s8 == 4) {
              const float* xr = xb1 + (size_t)((ch+1)*TC + tt*16 + r15)*DIN + kg*8;
#pragma unroll
              for (int ko = 0; ko < 4; ++ko) {
                const float4* xp = (const float4*)(xr + ko*32);
                lv[2*ko]   = xp[0];
                lv[2*ko+1] = xp[1];
              }
            }
            if (s8 == 6) {
#pragma unroll
              for (int ko = 0; ko < 2; ++ko) {
                float4 v0 = lv[2*ko], v1 = lv[2*ko+1];
                afrB[ko].x = pk2(v0.x, v0.y); afrB[ko].y = pk2(v0.z, v0.w);
                afrB[ko].z = pk2(v1.x, v1.y); afrB[ko].w = pk2(v1.z, v1.w);
              }
            }
            if (s8 == 7) {
#pragma unroll
              for (int ko = 2; ko < 4; ++ko) {
                float4 v0 = lv[2*ko], v1 = lv[2*ko+1];
                afrB[ko].x = pk2(v0.x, v0.y); afrB[ko].y = pk2(v0.z, v0.w);
                afrB[ko].z = pk2(v1.x, v1.y); afrB[ko].w = pk2(v1.z, v1.w);
              }
            }
          } else {
            const int nt = s8 >> 1;      // compile-time (s8 unrolled)
            if ((s8 & 1) == 0) {
              aaccA = MF(afrA[1], bfA[nt][1], MF(afrA[0], bfA[nt][0], Z));
              aaccB = MF(afrB[1], bfA[nt][1], MF(afrB[0], bfA[nt][0], Z));
            } else {
              aaccA = MF(afrA[3], bfA[nt][3], MF(afrA[2], bfA[nt][2], aaccA));
              aaccB = MF(afrB[3], bfA[nt][3], MF(afrB[2], bfA[nt][2], aaccB));
              int n = wv * 64 + nt * 16 + r15;
              int t0 = tt*16 + kg*4;
              u32 off = (u32)(n*64 + ((t0*2) ^ swz(n)));
              uint2 pwA; pwA.x = pk2(aaccA[0], aaccA[1]); pwA.y = pk2(aaccA[2], aaccA[3]);
              uint2 pwB; pwB.x = pk2(aaccB[0], aaccB[1]); pwB.y = pk2(aaccB[2], aaccB[3]);
              *(uint2*)(xgN0 + off) = pwA;
              *(uint2*)(xgN1 + off) = pwB;
            }
          }
        }

        // ---- recurrence step, element 0 and element 1 (independent chains) ----
        uint4 p0 = *(const uint4*)(lds + rdh0 + kg*16);
        uint4 p1 = *(const uint4*)(lds + rdh0 + 64 + kg*16);
        uint4 q0 = *(const uint4*)(lds + rdh1 + kg*16);
        uint4 q1 = *(const uint4*)(lds + rdh1 + 64 + kg*16);
        i32x4 ai0 = MFI8(p0, bi8[0][0], ZI);
        i32x4 af0 = MFI8(p0, bi8[1][0], ZI);
        i32x4 ag0 = MFI8(p0, bi8[2][0], ZI);
        i32x4 ao0 = MFI8(p0, bi8[3][0], ZI);
        i32x4 ai1 = MFI8(q0, bi8[0][0], ZI);
        i32x4 af1 = MFI8(q0, bi8[1][0], ZI);
        i32x4 ag1 = MFI8(q0, bi8[2][0], ZI);
        i32x4 ao1 = MFI8(q0, bi8[3][0], ZI);
        ai0 = MFI8(p1, bi8[0][1], ai0);
        af0 = MFI8(p1, bi8[1][1], af0);
        ag0 = MFI8(p1, bi8[2][1], ag0);
        ao0 = MFI8(p1, bi8[3][1], ao0);
        ai1 = MFI8(q1, bi8[0][1], ai1);
        af1 = MFI8(q1, bi8[1][1], af1);
        ag1 = MFI8(q1, bi8[2][1], ag1);
        ao1 = MFI8(q1, bi8[3][1], ao1);
        // kg-split nonlinearity, element 0
        int aw0 = (kg == 0) ? ai0[0] : (kg == 1) ? af0[0]
                : (kg == 2) ? ag0[0] : ao0[0];
        float g0 = __builtin_fmaf((float)aw0, dqo, (float)xh0[s8]);
        float y0 = __builtin_amdgcn_rcpf(1.f + fexp2(g0));
        float s0 = __builtin_fmaf(cA, y0, cB);
        float sf0 = __shfl_xor(s0, 16, 64);
        float sg0 = __shfl_xor(s0, 32, 64);
        float so0 = __shfl_xor(s0, 48, 64);
        c0 = __builtin_fmaf(sf0, c0, s0 * sg0);
        float th0 = __builtin_fmaf(2.f,
                      __builtin_amdgcn_rcpf(1.f + fexp2(c0 * -2.885390082f)), -1.f);
        float hv0 = so0 * th0;
        lasth0 = hv0;
        int qz0 = (int)__builtin_rintf(hv0 * 127.f);
        if (l < 16) *(char*)(lds + wrh0 + j) = (char)qz0;
        // kg-split nonlinearity, element 1
        int aw1 = (kg == 0) ? ai1[0] : (kg == 1) ? af1[0]
                : (kg == 2) ? ag1[0] : ao1[0];
        float g1 = __builtin_fmaf((float)aw1, dqo, (float)xh1[s8]);
        float y1 = __builtin_amdgcn_rcpf(1.f + fexp2(g1));
        float s1 = __builtin_fmaf(cA, y1, cB);
        float sf1 = __shfl_xor(s1, 16, 64);
        float sg1 = __shfl_xor(s1, 32, 64);
        float so1 = __shfl_xor(s1, 48, 64);
        c1 = __builtin_fmaf(sf1, c1, s1 * sg1);
        float th1 = __builtin_fmaf(2.f,
                      __builtin_amdgcn_rcpf(1.f + fexp2(c1 * -2.885390082f)), -1.f);
        float hv1 = so1 * th1;
        lasth1 = hv1;
        int qz1 = (int)__builtin_rintf(hv1 * 127.f);
        if (l < 16) *(char*)(lds + wrh1 + j) = (char)qz1;
        u32 t0s = rdh0; rdh0 = wrh0; wrh0 = t0s;
        u32 t1s = rdh1; rdh1 = wrh1; wrh1 = t1s;
        step_barrier();
      }
    }
    cur ^= 1;
  }

  // ---- publish exact final h (f16) and tail for both elements ----
  if (l < 16) {
    *(__fp16*)(lds + HF2 + j * 2)       = (__fp16)lasth0;
    *(__fp16*)(lds + HF2 + 256 + j * 2) = (__fp16)lasth1;
  }
  __syncthreads();
  if (tid < 2 * DH) {
    int e = tid >> 7, n = tid & 127;
    const u32* hf = (const u32*)(lds + HF2 + e * 256);
    float acc = 0.f;
#pragma unroll 8
    for (int kk = 0; kk < 64; ++kk) {
      half2_t h2v = __builtin_bit_cast(half2_t, hf[kk]);
      acc = __builtin_fmaf((float)h2v[0], w_out[(2*kk)*DH + n],
            __builtin_fmaf((float)h2v[1], w_out[(2*kk+1)*DH + n], acc));
    }
    out[(e ? b1 : b0) * DH + n] = acc;
  }
}

extern "C" void kernel_launch(void* const* d_in, const int* in_sizes, int n_in,
                              void* d_out, int out_size, void* d_ws, size_t ws_size,
                              hipStream_t stream) {
  const float* x    = (const float*)d_in[0];
  const float* x2i  = (const float*)d_in[1];
  const float* x2f  = (const float*)d_in[2];
  const float* x2g  = (const float*)d_in[3];
  const float* x2o  = (const float*)d_in[4];
  const float* h2i  = (const float*)d_in[5];
  const float* h2f  = (const float*)d_in[6];
  const float* h2g  = (const float*)d_in[7];
  const float* h2o  = (const float*)d_in[8];
  const float* wout = (const float*)d_in[9];

  u32*   wxT = (u32*)d_ws;                 // 32768 u32 = 128 KB
  u32*   whI = wxT + NC * 64;              // 16384 u32 =  64 KB
  float* dqs = (float*)(whI + NC * 32);    //   512 f32 =   2 KB

  (void)hipFuncSetAttribute((const void*)lstm_fused,
                            hipFuncAttributeMaxDynamicSharedMemorySize, LDS_TOTAL);

  pack_w<<<64, 512, 0, stream>>>(x2i, x2f, x2g, x2o, wxT);
  pack_whi8<<<1, 512, 0, stream>>>(h2i, h2f, h2g, h2o, whI, dqs);
  lstm_fused<<<NBATCH/2, 512, LDS_TOTAL, stream>>>(x, wxT, whI, dqs, wout, (float*)d_out);
}

// Round 16
// 404.439 us; speedup vs baseline: 1.0524x; 1.0524x over previous
//
#include <hip/hip_runtime.h>

typedef unsigned int u32;
typedef __fp16 half2_t __attribute__((ext_vector_type(2)));
typedef __fp16 half8_t __attribute__((ext_vector_type(8)));
typedef float  f32x4   __attribute__((ext_vector_type(4)));
typedef int    i32x4   __attribute__((ext_vector_type(4)));

#define DIN 128
#define DH  128
#define SEQL 512
#define NBATCH 256
#define NC  512          // 4*DH fused gate columns
#define TC  32           // timesteps per chunk (2 elements -> smaller chunks)
#define NCHUNK (SEQL/TC) // 16

// LDS: xgT e0 @ {0, 32768}, e1 @ {65536, 98304} ([col][64 B of t] swizzled)
#define HOFF 131072      // h i8 dbufs: e0 @ HOFF (2x128B), e1 @ HOFF+256
#define HF2  (131072 + 512)   // final f16 h: e0 @ +512, e1 @ +768
#define LDS_TOTAL (131072 + 1024)

__device__ __forceinline__ u32 pk2(float a, float b) {
  half2_t h = __builtin_amdgcn_cvt_pkrtz(a, b);
  return __builtin_bit_cast(u32, h);
}

__device__ __forceinline__ float fexp2(float x) {
#if defined(__has_builtin) && __has_builtin(__builtin_amdgcn_exp2f)
  return __builtin_amdgcn_exp2f(x);
#else
  return __builtin_exp2f(x);
#endif
}

// 64-B-row XOR swizzle: 16B-granule position = (t16 ^ ((col ^ col>>2)&3))
__device__ __forceinline__ u32 swz(int col) {
  return ((u32)((col ^ (col >> 2)) & 3)) << 4;
}

// raw step barrier: publish LDS writes (lgkm only), keep global loads in flight
__device__ __forceinline__ void step_barrier() {
  asm volatile("s_waitcnt lgkmcnt(0)" ::: "memory");
  __builtin_amdgcn_s_barrier();
  asm volatile("" ::: "memory");
}

#define MF(A, B, C) __builtin_amdgcn_mfma_f32_16x16x32_f16( \
    __builtin_bit_cast(half8_t, A), __builtin_bit_cast(half8_t, B), C, 0, 0, 0)
#define MFI8(A, B, C) __builtin_amdgcn_mfma_i32_16x16x64_i8( \
    __builtin_bit_cast(i32x4, A), __builtin_bit_cast(i32x4, B), C, 0, 0, 0)

// Pack fused x-projection weights (f16 pairs, pre-scaled by exp2 constants)
__global__ void pack_w(const float* __restrict__ x2i, const float* __restrict__ x2f,
                       const float* __restrict__ x2g, const float* __restrict__ x2o,
                       u32* __restrict__ wxT) {
  int idx = blockIdx.x * blockDim.x + threadIdx.x;   // 0..32767
  if (idx >= NC * 64) return;
  int j = idx >> 6, kk = idx & 63;
  int g = j >> 7, jjj = j & 127;
  const float* wx = (g == 0) ? x2i : (g == 1) ? x2f : (g == 2) ? x2g : x2o;
  float s = (g == 2) ? -2.885390082f : -1.442695041f;
  wxT[idx] = pk2(s * wx[(2*kk)*DH + jjj], s * wx[(2*kk+1)*DH + jjj]);
}

// Quantize recurrence weights to i8 (per-column scale; dequant folds exp2 const)
__global__ void pack_whi8(const float* __restrict__ h2i, const float* __restrict__ h2f,
                          const float* __restrict__ h2g, const float* __restrict__ h2o,
                          u32* __restrict__ whI, float* __restrict__ dqs) {
  int j = blockIdx.x * blockDim.x + threadIdx.x;   // 0..511 fused col
  if (j >= NC) return;
  int g = j >> 7, jj = j & 127;
  const float* wh = (g == 0) ? h2i : (g == 1) ? h2f : (g == 2) ? h2g : h2o;
  float amax = 1e-20f;
  for (int k = 0; k < DH; ++k) amax = fmaxf(amax, fabsf(wh[k*DH + jj]));
  float s = 127.f / amax;
  for (int kk = 0; kk < 32; ++kk) {
    u32 wword = 0;
#pragma unroll
    for (int t = 0; t < 4; ++t) {
      int q = (int)__builtin_rintf(wh[(4*kk + t)*DH + jj] * s);
      wword |= ((u32)(q & 0xFF)) << (8 * t);
    }
    whI[j*32 + kk] = wword;
  }
  dqs[j] = (amax / 16129.f) * ((g == 2) ? -2.885390082f : -1.442695041f);
}

// Two batch elements per block (in-wave ILP). Phase A STAGGERED: one
// (element, tile) per m-group -> one lv/afr set live at a time.
__global__ __launch_bounds__(512)
__attribute__((amdgpu_waves_per_eu(2, 2)))
void lstm_fused(
    const float* __restrict__ x, const u32* __restrict__ wxT,
    const u32* __restrict__ whI, const float* __restrict__ dqs,
    const float* __restrict__ w_out, float* __restrict__ out) {
  extern __shared__ char lds[];

  const int tid = threadIdx.x;
  const int b0  = blockIdx.x * 2, b1 = b0 + 1;
  const int l   = tid & 63, wv = tid >> 6;
  const int kg  = l >> 4, r15 = l & 15;
  const int j   = wv * 16 + r15;   // hidden index this lane owns

  // i8 recurrence B-frags (shared by both elements)
  uint4 bi8[4][2];
#pragma unroll
  for (int g = 0; g < 4; ++g) {
    const uint4* wp = (const uint4*)(whI + (g * DH + j) * 32);
    bi8[g][0] = wp[kg];
    bi8[g][1] = wp[4 + kg];
  }
  const float dqo = dqs[kg * DH + j];
  const float cA = (kg == 2) ? 2.f : 1.f;
  const float cB = (kg == 2) ? -1.f : 0.f;
  // Phase-A B-frags (shared, persistent)
  uint4 bfA[4][4];
#pragma unroll
  for (int nt = 0; nt < 4; ++nt) {
    int n = wv * 64 + nt * 16 + r15;
#pragma unroll
    for (int ko = 0; ko < 4; ++ko)
      bfA[nt][ko] = *(const uint4*)(wxT + n*64 + ko*16 + kg*4);
  }

  if (tid < 128) ((u32*)(lds + HOFF))[tid] = 0u;   // zero all 4 h buffers
  float c0 = 0.f, c1 = 0.f, lasth0 = 0.f, lasth1 = 0.f;
  u32 rdh0 = HOFF,       wrh0 = HOFF + 128;
  u32 rdh1 = HOFF + 256, wrh1 = HOFF + 384;
  const float* xb0 = x + (size_t)b0 * SEQL * DIN;
  const float* xb1 = x + (size_t)b1 * SEQL * DIN;
  const f32x4 Z  = {0.f, 0.f, 0.f, 0.f};
  const i32x4 ZI = {0, 0, 0, 0};
  __syncthreads();

  // ---- standalone phase A for chunk 0, both elements ----
#pragma unroll 1
  for (int e = 0; e < 2; ++e) {
    const float* xbe = e ? xb1 : xb0;
    char* dst = lds + e * 65536;      // buffer 0 of element e
#pragma unroll 1
    for (int tt = 0; tt < 2; ++tt) {
      uint4 afr0[4];
#pragma unroll
      for (int ko = 0; ko < 4; ++ko) {
        const float4* xp = (const float4*)(xbe + (size_t)(tt*16 + r15)*DIN + ko*32 + kg*8);
        float4 v0 = xp[0], v1 = xp[1];
        afr0[ko].x = pk2(v0.x, v0.y); afr0[ko].y = pk2(v0.z, v0.w);
        afr0[ko].z = pk2(v1.x, v1.y); afr0[ko].w = pk2(v1.z, v1.w);
      }
#pragma unroll
      for (int nt = 0; nt < 4; ++nt) {
        int n = wv * 64 + nt * 16 + r15;
        f32x4 acc = MF(afr0[0], bfA[nt][0], Z);
        acc = MF(afr0[1], bfA[nt][1], acc);
        acc = MF(afr0[2], bfA[nt][2], acc);
        acc = MF(afr0[3], bfA[nt][3], acc);
        int t0 = tt*16 + kg*4;
        u32 off = (u32)(n*64 + ((t0*2) ^ swz(n)));
        uint2 pw; pw.x = pk2(acc[0], acc[1]); pw.y = pk2(acc[2], acc[3]);
        *(uint2*)(dst + off) = pw;
      }
    }
  }
  __syncthreads();

  int cur = 0;
#pragma unroll 1
  for (int ch = 0; ch < NCHUNK; ++ch) {
    char* xgC0 = lds + cur * 32768;
    char* xgC1 = lds + 65536 + cur * 32768;
    const bool doA = (ch + 1 < NCHUNK);
    float4 lv[8];      // ONE staged-load set (staggered across m-groups)
    uint4  afr[4];     // ONE f16 A-frag set
    f32x4  aacc;

#pragma unroll 1
    for (int m = 0; m < 4; ++m) {
      const int ea  = m & 1;        // phase-A element this m-group serves
      const int tta = m >> 1;       // phase-A tile (tt) this m-group serves
      const int cg = kg * DH + j;   // own-gate column
      half8_t xh0 = __builtin_bit_cast(half8_t,
          *(const uint4*)(xgC0 + cg*64 + ((m*16) ^ swz(cg))));
      half8_t xh1 = __builtin_bit_cast(half8_t,
          *(const uint4*)(xgC1 + cg*64 + ((m*16) ^ swz(cg))));
#pragma unroll
      for (int s8 = 0; s8 < 8; ++s8) {
        // ---- interleaved phase A (chunk ch+1): one (elem,tile)/m-group ----
        if (doA) {
          if (s8 == 0) {
            const float* xbe = ea ? xb1 : xb0;
            const float* xr = xbe + (size_t)((ch+1)*TC + tta*16 + r15)*DIN + kg*8;
#pragma unroll
            for (int ko = 0; ko < 4; ++ko) {
              const float4* xp = (const float4*)(xr + ko*32);
              lv[2*ko]   = xp[0];
              lv[2*ko+1] = xp[1];
            }
          }
          if (s8 == 2) {
#pragma unroll
            for (int ko = 0; ko < 2; ++ko) {
              float4 v0 = lv[2*ko], v1 = lv[2*ko+1];
              afr[ko].x = pk2(v0.x, v0.y); afr[ko].y = pk2(v0.z, v0.w);
              afr[ko].z = pk2(v1.x, v1.y); afr[ko].w = pk2(v1.z, v1.w);
            }
          }
          if (s8 == 3) {
#pragma unroll
            for (int ko = 2; ko < 4; ++ko) {
              float4 v0 = lv[2*ko], v1 = lv[2*ko+1];
              afr[ko].x = pk2(v0.x, v0.y); afr[ko].y = pk2(v0.z, v0.w);
              afr[ko].z = pk2(v1.x, v1.y); afr[ko].w = pk2(v1.z, v1.w);
            }
          }
          if (s8 >= 4) {
            const int nt = s8 - 4;   // compile-time (s8 unrolled)
            aacc = MF(afr[0], bfA[nt][0], Z);
            aacc = MF(afr[1], bfA[nt][1], aacc);
            aacc = MF(afr[2], bfA[nt][2], aacc);
            aacc = MF(afr[3], bfA[nt][3], aacc);
            int n = wv * 64 + nt * 16 + r15;
            int t0 = tta*16 + kg*4;
            u32 off = (u32)(n*64 + ((t0*2) ^ swz(n)));
            uint2 pw; pw.x = pk2(aacc[0], aacc[1]); pw.y = pk2(aacc[2], aacc[3]);
            char* xgN = lds + (ea ? 65536 : 0) + (cur ^ 1) * 32768;
            *(uint2*)(xgN + off) = pw;
          }
        }

        // ---- recurrence step, element 0 and element 1 (independent chains) ----
        uint4 p0 = *(const uint4*)(lds + rdh0 + kg*16);
        uint4 p1 = *(const uint4*)(lds + rdh0 + 64 + kg*16);
        uint4 q0 = *(const uint4*)(lds + rdh1 + kg*16);
        uint4 q1 = *(const uint4*)(lds + rdh1 + 64 + kg*16);
        i32x4 ai0 = MFI8(p0, bi8[0][0], ZI);
        i32x4 af0 = MFI8(p0, bi8[1][0], ZI);
        i32x4 ag0 = MFI8(p0, bi8[2][0], ZI);
        i32x4 ao0 = MFI8(p0, bi8[3][0], ZI);
        i32x4 ai1 = MFI8(q0, bi8[0][0], ZI);
        i32x4 af1 = MFI8(q0, bi8[1][0], ZI);
        i32x4 ag1 = MFI8(q0, bi8[2][0], ZI);
        i32x4 ao1 = MFI8(q0, bi8[3][0], ZI);
        ai0 = MFI8(p1, bi8[0][1], ai0);
        af0 = MFI8(p1, bi8[1][1], af0);
        ag0 = MFI8(p1, bi8[2][1], ag0);
        ao0 = MFI8(p1, bi8[3][1], ao0);
        ai1 = MFI8(q1, bi8[0][1], ai1);
        af1 = MFI8(q1, bi8[1][1], af1);
        ag1 = MFI8(q1, bi8[2][1], ag1);
        ao1 = MFI8(q1, bi8[3][1], ao1);
        // kg-split nonlinearity, element 0
        int aw0 = (kg == 0) ? ai0[0] : (kg == 1) ? af0[0]
                : (kg == 2) ? ag0[0] : ao0[0];
        float g0 = __builtin_fmaf((float)aw0, dqo, (float)xh0[s8]);
        float y0 = __builtin_amdgcn_rcpf(1.f + fexp2(g0));
        float s0 = __builtin_fmaf(cA, y0, cB);
        float sf0 = __shfl_xor(s0, 16, 64);
        float sg0 = __shfl_xor(s0, 32, 64);
        float so0 = __shfl_xor(s0, 48, 64);
        c0 = __builtin_fmaf(sf0, c0, s0 * sg0);
        float th0 = __builtin_fmaf(2.f,
                      __builtin_amdgcn_rcpf(1.f + fexp2(c0 * -2.885390082f)), -1.f);
        float hv0 = so0 * th0;
        lasth0 = hv0;
        int qz0 = (int)__builtin_rintf(hv0 * 127.f);
        if (l < 16) *(char*)(lds + wrh0 + j) = (char)qz0;
        // kg-split nonlinearity, element 1
        int aw1 = (kg == 0) ? ai1[0] : (kg == 1) ? af1[0]
                : (kg == 2) ? ag1[0] : ao1[0];
        float g1 = __builtin_fmaf((float)aw1, dqo, (float)xh1[s8]);
        float y1 = __builtin_amdgcn_rcpf(1.f + fexp2(g1));
        float s1 = __builtin_fmaf(cA, y1, cB);
        float sf1 = __shfl_xor(s1, 16, 64);
        float sg1 = __shfl_xor(s1, 32, 64);
        float so1 = __shfl_xor(s1, 48, 64);
        c1 = __builtin_fmaf(sf1, c1, s1 * sg1);
        float th1 = __builtin_fmaf(2.f,
                      __builtin_amdgcn_rcpf(1.f + fexp2(c1 * -2.885390082f)), -1.f);
        float hv1 = so1 * th1;
        lasth1 = hv1;
        int qz1 = (int)__builtin_rintf(hv1 * 127.f);
        if (l < 16) *(char*)(lds + wrh1 + j) = (char)qz1;
        u32 t0s = rdh0; rdh0 = wrh0; wrh0 = t0s;
        u32 t1s = rdh1; rdh1 = wrh1; wrh1 = t1s;
        step_barrier();
      }
    }
    cur ^= 1;
  }

  // ---- publish exact final h (f16) and tail for both elements ----
  if (l < 16) {
    *(__fp16*)(lds + HF2 + j * 2)       = (__fp16)lasth0;
    *(__fp16*)(lds + HF2 + 256 + j * 2) = (__fp16)lasth1;
  }
  __syncthreads();
  if (tid < 2 * DH) {
    int e = tid >> 7, n = tid & 127;
    const u32* hf = (const u32*)(lds + HF2 + e * 256);
    float acc = 0.f;
#pragma unroll 8
    for (int kk = 0; kk < 64; ++kk) {
      half2_t h2v = __builtin_bit_cast(half2_t, hf[kk]);
      acc = __builtin_fmaf((float)h2v[0], w_out[(2*kk)*DH + n],
            __builtin_fmaf((float)h2v[1], w_out[(2*kk+1)*DH + n], acc));
    }
    out[(e ? b1 : b0) * DH + n] = acc;
  }
}

extern "C" void kernel_launch(void* const* d_in, const int* in_sizes, int n_in,
                              void* d_out, int out_size, void* d_ws, size_t ws_size,
                              hipStream_t stream) {
  const float* x    = (const float*)d_in[0];
  const float* x2i  = (const float*)d_in[1];
  const float* x2f  = (const float*)d_in[2];
  const float* x2g  = (const float*)d_in[3];
  const float* x2o  = (const float*)d_in[4];
  const float* h2i  = (const float*)d_in[5];
  const float* h2f  = (const float*)d_in[6];
  const float* h2g  = (const float*)d_in[7];
  const float* h2o  = (const float*)d_in[8];
  const float* wout = (const float*)d_in[9];

  u32*   wxT = (u32*)d_ws;                 // 32768 u32 = 128 KB
  u32*   whI = wxT + NC * 64;              // 16384 u32 =  64 KB
  float* dqs = (float*)(whI + NC * 32);    //   512 f32 =   2 KB

  (void)hipFuncSetAttribute((const void*)lstm_fused,
                            hipFuncAttributeMaxDynamicSharedMemorySize, LDS_TOTAL);

  pack_w<<<64, 512, 0, stream>>>(x2i, x2f, x2g, x2o, wxT);
  pack_whi8<<<1, 512, 0, stream>>>(h2i, h2f, h2g, h2o, whI, dqs);
  lstm_fused<<<NBATCH/2, 512, LDS_TOTAL, stream>>>(x, wxT, whI, dqs, wout, (float*)d_out);
}

// Round 17
// 329.000 us; speedup vs baseline: 1.2937x; 1.2293x over previous
//
#include <hip/hip_runtime.h>

typedef unsigned int u32;
typedef __fp16 half2_t __attribute__((ext_vector_type(2)));
typedef __fp16 half8_t __attribute__((ext_vector_type(8)));
typedef float  f32x4   __attribute__((ext_vector_type(4)));
typedef int    i32x4   __attribute__((ext_vector_type(4)));

#define DIN 128
#define DH  128
#define SEQL 512
#define NBATCH 256
#define NC  512          // 4*DH fused gate columns
#define TC  64           // timesteps per chunk
#define NCHUNK (SEQL/TC) // 8

#define HOFF 131072              // i8 h dbuf after 2 xgT buffers (2 x 128 B)
#define HF2  (131072 + 256)      // final f16 h for tail (256 B)
#define LDS_TOTAL (131072 + 256 + 256)

__device__ __forceinline__ u32 pk2(float a, float b) {
  half2_t h = __builtin_amdgcn_cvt_pkrtz(a, b);
  return __builtin_bit_cast(u32, h);
}

__device__ __forceinline__ float fexp2(float x) {
#if defined(__has_builtin) && __has_builtin(__builtin_amdgcn_exp2f)
  return __builtin_amdgcn_exp2f(x);
#else
  return __builtin_exp2f(x);
#endif
}

// raw step barrier: publish LDS writes (lgkm only), keep global loads in flight
__device__ __forceinline__ void step_barrier() {
  asm volatile("s_waitcnt lgkmcnt(0)" ::: "memory");
  __builtin_amdgcn_s_barrier();
  asm volatile("" ::: "memory");
}

#define MF(A, B, C) __builtin_amdgcn_mfma_f32_16x16x32_f16( \
    __builtin_bit_cast(half8_t, A), __builtin_bit_cast(half8_t, B), C, 0, 0, 0)
#define MFI8(A, B, C) __builtin_amdgcn_mfma_i32_16x16x64_i8( \
    __builtin_bit_cast(i32x4, A), __builtin_bit_cast(i32x4, B), C, 0, 0, 0)

// Pack fused x-projection weights (f16 pairs, pre-scaled by exp2 constants)
__global__ void pack_w(const float* __restrict__ x2i, const float* __restrict__ x2f,
                       const float* __restrict__ x2g, const float* __restrict__ x2o,
                       u32* __restrict__ wxT) {
  int idx = blockIdx.x * blockDim.x + threadIdx.x;   // 0..32767
  if (idx >= NC * 64) return;
  int j = idx >> 6, kk = idx & 63;
  int g = j >> 7, jjj = j & 127;
  const float* wx = (g == 0) ? x2i : (g == 1) ? x2f : (g == 2) ? x2g : x2o;
  float s = (g == 2) ? -2.885390082f : -1.442695041f;
  wxT[idx] = pk2(s * wx[(2*kk)*DH + jjj], s * wx[(2*kk+1)*DH + jjj]);
}

// Quantize recurrence weights to i8 (per-column scale; dequant folds exp2 const)
__global__ void pack_whi8(const float* __restrict__ h2i, const float* __restrict__ h2f,
                          const float* __restrict__ h2g, const float* __restrict__ h2o,
                          u32* __restrict__ whI, float* __restrict__ dqs) {
  int j = blockIdx.x * blockDim.x + threadIdx.x;   // 0..511 fused col
  if (j >= NC) return;
  int g = j >> 7, jj = j & 127;
  const float* wh = (g == 0) ? h2i : (g == 1) ? h2f : (g == 2) ? h2g : h2o;
  float amax = 1e-20f;
  for (int k = 0; k < DH; ++k) amax = fmaxf(amax, fabsf(wh[k*DH + jj]));
  float s = 127.f / amax;
  for (int kk = 0; kk < 32; ++kk) {
    u32 wword = 0;
#pragma unroll
    for (int t = 0; t < 4; ++t) {
      int q = (int)__builtin_rintf(wh[(4*kk + t)*DH + jj] * s);
      wword |= ((u32)(q & 0xFF)) << (8 * t);
    }
    whI[j*32 + kk] = wword;
  }
  dqs[j] = (amax / 16129.f) * ((g == 2) ? -2.885390082f : -1.442695041f);
}

// 4 waves (one/SIMD, 512-VGPR budget). Wave wv owns j in [32wv, 32wv+32) as
// TWO 16-col tiles -> two independent nonlin/c chains per lane (in-element
// ILP; grid stays 256). h-reads shared by both tiles. Phase A interleaved.
__global__ __launch_bounds__(256)
__attribute__((amdgpu_waves_per_eu(1, 1)))
void lstm_fused(
    const float* __restrict__ x, const u32* __restrict__ wxT,
    const u32* __restrict__ whI, const float* __restrict__ dqs,
    const float* __restrict__ w_out, float* __restrict__ out) {
  extern __shared__ char lds[];

  const int tid = threadIdx.x;
  const int b   = blockIdx.x;
  const int l   = tid & 63, wv = tid >> 6;   // 4 waves
  const int kg  = l >> 4, r15 = l & 15;
  const int jA  = wv * 32 + r15;       // col tile A
  const int jB  = jA + 16;             // col tile B

  // i8 recurrence B-frags: [gate][tile][k-slice]  (64 VGPRs)
  uint4 bi8[4][2][2];
#pragma unroll
  for (int g = 0; g < 4; ++g) {
    const uint4* wpA = (const uint4*)(whI + (g * DH + jA) * 32);
    const uint4* wpB = (const uint4*)(whI + (g * DH + jB) * 32);
    bi8[g][0][0] = wpA[kg];  bi8[g][0][1] = wpA[4 + kg];
    bi8[g][1][0] = wpB[kg];  bi8[g][1][1] = wpB[4 + kg];
  }
  const float dqoA = dqs[kg * DH + jA];
  const float dqoB = dqs[kg * DH + jB];
  const float cA = (kg == 2) ? 2.f : 1.f;
  const float cB = (kg == 2) ? -1.f : 0.f;
  // Phase-A B-frags: this wave's 8 n-tiles (128 VGPRs, persistent)
  uint4 bfA[8][4];
#pragma unroll
  for (int nt = 0; nt < 8; ++nt) {
    int n = wv * 128 + nt * 16 + r15;
#pragma unroll
    for (int ko = 0; ko < 4; ++ko)
      bfA[nt][ko] = *(const uint4*)(wxT + n*64 + ko*16 + kg*4);
  }

  if (tid < 64) ((u32*)(lds + HOFF))[tid] = 0u;   // zero both i8 h buffers
  float c0 = 0.f, c1 = 0.f, lasthA = 0.f, lasthB = 0.f;
  u32 rdh = HOFF;          // current h (i8[128])
  u32 wrh = HOFF + 128;    // next h
  const float* xb = x + (size_t)b * SEQL * DIN;
  const f32x4 Z  = {0.f, 0.f, 0.f, 0.f};
  const i32x4 ZI = {0, 0, 0, 0};
  __syncthreads();

  // ---- standalone phase A for chunk 0 -> buffer 0 ----
#pragma unroll 1
  for (int tt = 0; tt < 4; ++tt) {
    uint4 afr0[4];
#pragma unroll
    for (int ko = 0; ko < 4; ++ko) {
      const float4* xp = (const float4*)(xb + (size_t)(tt*16 + r15)*DIN + ko*32 + kg*8);
      float4 v0 = xp[0], v1 = xp[1];
      afr0[ko].x = pk2(v0.x, v0.y); afr0[ko].y = pk2(v0.z, v0.w);
      afr0[ko].z = pk2(v1.x, v1.y); afr0[ko].w = pk2(v1.z, v1.w);
    }
#pragma unroll
    for (int nt = 0; nt < 8; ++nt) {
      int n = wv * 128 + nt * 16 + r15;
      f32x4 acc = MF(afr0[0], bfA[nt][0], Z);
      acc = MF(afr0[1], bfA[nt][1], acc);
      acc = MF(afr0[2], bfA[nt][2], acc);
      acc = MF(afr0[3], bfA[nt][3], acc);
      int t0 = tt*16 + kg*4;
      u32 off = (u32)(n*128 + ((t0*2) ^ ((n & 7) << 4)));
      uint2 pw; pw.x = pk2(acc[0], acc[1]); pw.y = pk2(acc[2], acc[3]);
      *(uint2*)(lds + off) = pw;
    }
  }
  __syncthreads();

  int cur = 0;
#pragma unroll 1
  for (int ch = 0; ch < NCHUNK; ++ch) {
    char* xgC = lds + cur * 65536;
    char* xgN = lds + (cur ^ 1) * 65536;
    const bool doA = (ch + 1 < NCHUNK);
    float4 lv[8];    // staged x loads (even m)
    uint4  afr[4];   // f16 A-frags (built even m, consumed odd m)

#pragma unroll 1
    for (int m = 0; m < 8; ++m) {
      const int tt = m >> 1;
      // own-gate xg columns for both tiles, timesteps [8m, 8m+8)
      const int cgA = kg * DH + jA, cgB = kg * DH + jB;
      half8_t xhA = __builtin_bit_cast(half8_t,
          *(const uint4*)(xgC + cgA*128 + ((m*16) ^ ((cgA & 7) << 4))));
      half8_t xhB = __builtin_bit_cast(half8_t,
          *(const uint4*)(xgC + cgB*128 + ((m*16) ^ ((cgB & 7) << 4))));
#pragma unroll
      for (int s8 = 0; s8 < 8; ++s8) {
        // ---- interleaved phase A (chunk ch+1) ----
        if (doA) {
          if ((m & 1) == 0) {
            if (s8 == 0) {
              const float* xr = xb + (size_t)((ch+1)*TC + tt*16 + r15)*DIN + kg*8;
#pragma unroll
              for (int ko = 0; ko < 4; ++ko) {
                const float4* xp = (const float4*)(xr + ko*32);
                lv[2*ko]   = xp[0];
                lv[2*ko+1] = xp[1];
              }
            }
            if (s8 == 2) {
#pragma unroll
              for (int ko = 0; ko < 2; ++ko) {
                float4 v0 = lv[2*ko], v1 = lv[2*ko+1];
                afr[ko].x = pk2(v0.x, v0.y); afr[ko].y = pk2(v0.z, v0.w);
                afr[ko].z = pk2(v1.x, v1.y); afr[ko].w = pk2(v1.z, v1.w);
              }
            }
            if (s8 == 3) {
#pragma unroll
              for (int ko = 2; ko < 4; ++ko) {
                float4 v0 = lv[2*ko], v1 = lv[2*ko+1];
                afr[ko].x = pk2(v0.x, v0.y); afr[ko].y = pk2(v0.z, v0.w);
                afr[ko].z = pk2(v1.x, v1.y); afr[ko].w = pk2(v1.z, v1.w);
              }
            }
          } else {
            const int nt = s8;          // one n-tile per step (compile-time)
            f32x4 aacc = MF(afr[0], bfA[nt][0], Z);
            aacc = MF(afr[1], bfA[nt][1], aacc);
            aacc = MF(afr[2], bfA[nt][2], aacc);
            aacc = MF(afr[3], bfA[nt][3], aacc);
            int n = wv * 128 + nt * 16 + r15;
            int t0 = tt*16 + kg*4;
            u32 off = (u32)(n*128 + ((t0*2) ^ ((n & 7) << 4)));
            uint2 pw; pw.x = pk2(aacc[0], aacc[1]); pw.y = pk2(aacc[2], aacc[3]);
            *(uint2*)(xgN + off) = pw;
          }
        }

        // ---- recurrence step: 16 i8 MFMA (two col tiles, shared h reads) ----
        uint4 a0 = *(const uint4*)(lds + rdh + kg*16);
        uint4 a1 = *(const uint4*)(lds + rdh + 64 + kg*16);
        i32x4 aiA = MFI8(a0, bi8[0][0][0], ZI);
        i32x4 afA = MFI8(a0, bi8[1][0][0], ZI);
        i32x4 agA = MFI8(a0, bi8[2][0][0], ZI);
        i32x4 aoA = MFI8(a0, bi8[3][0][0], ZI);
        i32x4 aiB = MFI8(a0, bi8[0][1][0], ZI);
        i32x4 afB = MFI8(a0, bi8[1][1][0], ZI);
        i32x4 agB = MFI8(a0, bi8[2][1][0], ZI);
        i32x4 aoB = MFI8(a0, bi8[3][1][0], ZI);
        aiA = MFI8(a1, bi8[0][0][1], aiA);
        afA = MFI8(a1, bi8[1][0][1], afA);
        agA = MFI8(a1, bi8[2][0][1], agA);
        aoA = MFI8(a1, bi8[3][0][1], aoA);
        aiB = MFI8(a1, bi8[0][1][1], aiB);
        afB = MFI8(a1, bi8[1][1][1], afB);
        agB = MFI8(a1, bi8[2][1][1], agB);
        aoB = MFI8(a1, bi8[3][1][1], aoB);
        // kg-split nonlinearity, tile A and tile B (independent chains)
        int awA = (kg == 0) ? aiA[0] : (kg == 1) ? afA[0]
                : (kg == 2) ? agA[0] : aoA[0];
        int awB = (kg == 0) ? aiB[0] : (kg == 1) ? afB[0]
                : (kg == 2) ? agB[0] : aoB[0];
        float gA = __builtin_fmaf((float)awA, dqoA, (float)xhA[s8]);
        float gB = __builtin_fmaf((float)awB, dqoB, (float)xhB[s8]);
        float yA = __builtin_amdgcn_rcpf(1.f + fexp2(gA));
        float yB = __builtin_amdgcn_rcpf(1.f + fexp2(gB));
        float sA = __builtin_fmaf(cA, yA, cB);
        float sB = __builtin_fmaf(cA, yB, cB);
        float sfA = __shfl_xor(sA, 16, 64);
        float sgA = __shfl_xor(sA, 32, 64);
        float soA = __shfl_xor(sA, 48, 64);
        float sfB = __shfl_xor(sB, 16, 64);
        float sgB = __shfl_xor(sB, 32, 64);
        float soB = __shfl_xor(sB, 48, 64);
        c0 = __builtin_fmaf(sfA, c0, sA * sgA);
        c1 = __builtin_fmaf(sfB, c1, sB * sgB);
        float thA = __builtin_fmaf(2.f,
                      __builtin_amdgcn_rcpf(1.f + fexp2(c0 * -2.885390082f)), -1.f);
        float thB = __builtin_fmaf(2.f,
                      __builtin_amdgcn_rcpf(1.f + fexp2(c1 * -2.885390082f)), -1.f);
        float hvA = soA * thA;
        float hvB = soB * thB;
        lasthA = hvA; lasthB = hvB;
        int qA = (int)__builtin_rintf(hvA * 127.f);
        int qB = (int)__builtin_rintf(hvB * 127.f);
        if (l < 16) {
          *(char*)(lds + wrh + jA) = (char)qA;
          *(char*)(lds + wrh + jB) = (char)qB;
        }
        u32 tswap = rdh; rdh = wrh; wrh = tswap;
        step_barrier();
      }
    }
    cur ^= 1;
  }

  // ---- publish exact final h as f16, then tail: out[b][n] = h @ w_out ----
  if (l < 16) {
    *(__fp16*)(lds + HF2 + jA * 2) = (__fp16)lasthA;
    *(__fp16*)(lds + HF2 + jB * 2) = (__fp16)lasthB;
  }
  __syncthreads();
  if (tid < DH) {
    int n = tid;
    const u32* hf = (const u32*)(lds + HF2);   // final h (f16 pairs)
    float acc = 0.f;
#pragma unroll 8
    for (int kk = 0; kk < 64; ++kk) {
      half2_t h2v = __builtin_bit_cast(half2_t, hf[kk]);
      acc = __builtin_fmaf((float)h2v[0], w_out[(2*kk)*DH + n],
            __builtin_fmaf((float)h2v[1], w_out[(2*kk+1)*DH + n], acc));
    }
    out[b * DH + n] = acc;
  }
}

extern "C" void kernel_launch(void* const* d_in, const int* in_sizes, int n_in,
                              void* d_out, int out_size, void* d_ws, size_t ws_size,
                              hipStream_t stream) {
  const float* x    = (const float*)d_in[0];
  const float* x2i  = (const float*)d_in[1];
  const float* x2f  = (const float*)d_in[2];
  const float* x2g  = (const float*)d_in[3];
  const float* x2o  = (const float*)d_in[4];
  const float* h2i  = (const float*)d_in[5];
  const float* h2f  = (const float*)d_in[6];
  const float* h2g  = (const float*)d_in[7];
  const float* h2o  = (const float*)d_in[8];
  const float* wout = (const float*)d_in[9];

  u32*   wxT = (u32*)d_ws;                 // 32768 u32 = 128 KB
  u32*   whI = wxT + NC * 64;              // 16384 u32 =  64 KB
  float* dqs = (float*)(whI + NC * 32);    //   512 f32 =   2 KB

  (void)hipFuncSetAttribute((const void*)lstm_fused,
                            hipFuncAttributeMaxDynamicSharedMemorySize, LDS_TOTAL);

  pack_w<<<64, 512, 0, stream>>>(x2i, x2f, x2g, x2o, wxT);
  pack_whi8<<<1, 512, 0, stream>>>(h2i, h2f, h2g, h2o, whI, dqs);
  lstm_fused<<<NBATCH, 256, LDS_TOTAL, stream>>>(x, wxT, whI, dqs, wout, (float*)d_out);
}

// Round 18
// 260.189 us; speedup vs baseline: 1.6358x; 1.2645x over previous
//
#include <hip/hip_runtime.h>

typedef unsigned int u32;
typedef __fp16 half2_t __attribute__((ext_vector_type(2)));
typedef __fp16 half8_t __attribute__((ext_vector_type(8)));
typedef float  f32x4   __attribute__((ext_vector_type(4)));
typedef int    i32x4   __attribute__((ext_vector_type(4)));

#define DIN 128
#define DH  128
#define SEQL 512
#define NBATCH 256
#define NC  512          // 4*DH fused gate columns
#define TC  64           // timesteps per chunk
#define NCHUNK (SEQL/TC) // 8

#define HOFF 131072              // i8 h dbuf after 2 xgT buffers (2 x 128 B)
#define HF2  (131072 + 256)      // final f16 h for tail (256 B)
#define LDS_TOTAL (131072 + 256 + 256)

__device__ __forceinline__ u32 pk2(float a, float b) {
  half2_t h = __builtin_amdgcn_cvt_pkrtz(a, b);
  return __builtin_bit_cast(u32, h);
}

__device__ __forceinline__ float fexp2(float x) {
#if defined(__has_builtin) && __has_builtin(__builtin_amdgcn_exp2f)
  return __builtin_amdgcn_exp2f(x);
#else
  return __builtin_exp2f(x);
#endif
}

// raw step barrier: publish LDS writes (lgkm only), do NOT drain vmcnt --
// keeps phase-A global loads in flight across recurrence step barriers.
__device__ __forceinline__ void step_barrier() {
  asm volatile("s_waitcnt lgkmcnt(0)" ::: "memory");
  __builtin_amdgcn_s_barrier();
  asm volatile("" ::: "memory");
}

#define MF(A, B, C) __builtin_amdgcn_mfma_f32_16x16x32_f16( \
    __builtin_bit_cast(half8_t, A), __builtin_bit_cast(half8_t, B), C, 0, 0, 0)
#define MFI8(A, B, C) __builtin_amdgcn_mfma_i32_16x16x64_i8( \
    __builtin_bit_cast(i32x4, A), __builtin_bit_cast(i32x4, B), C, 0, 0, 0)

// Pack fused x-projection weights into f16-pair column-major image,
// PRE-SCALED by the exp2 conversion constants (i,f,o: -log2e; g: -2log2e).
__global__ void pack_w(const float* __restrict__ x2i, const float* __restrict__ x2f,
                       const float* __restrict__ x2g, const float* __restrict__ x2o,
                       u32* __restrict__ wxT) {
  int idx = blockIdx.x * blockDim.x + threadIdx.x;   // 0..32767
  if (idx >= NC * 64) return;
  int j = idx >> 6, kk = idx & 63;
  int g = j >> 7, jjj = j & 127;
  const float* wx = (g == 0) ? x2i : (g == 1) ? x2f : (g == 2) ? x2g : x2o;
  float s = (g == 2) ? -2.885390082f : -1.442695041f;
  wxT[idx] = pk2(s * wx[(2*kk)*DH + jjj], s * wx[(2*kk+1)*DH + jjj]);
}

// Quantize recurrence weights to i8, per-column scale; dequant scale folds
// 1/(127*127) and the exp2 gate constant.
__global__ void pack_whi8(const float* __restrict__ h2i, const float* __restrict__ h2f,
                          const float* __restrict__ h2g, const float* __restrict__ h2o,
                          u32* __restrict__ whI, float* __restrict__ dqs) {
  int j = blockIdx.x * blockDim.x + threadIdx.x;   // 0..511 fused col
  if (j >= NC) return;
  int g = j >> 7, jj = j & 127;
  const float* wh = (g == 0) ? h2i : (g == 1) ? h2f : (g == 2) ? h2g : h2o;
  float amax = 1e-20f;
  for (int k = 0; k < DH; ++k) amax = fmaxf(amax, fabsf(wh[k*DH + jj]));
  float s = 127.f / amax;
  for (int kk = 0; kk < 32; ++kk) {
    u32 wword = 0;
#pragma unroll
    for (int t = 0; t < 4; ++t) {
      int q = (int)__builtin_rintf(wh[(4*kk + t)*DH + jj] * s);
      wword |= ((u32)(q & 0xFF)) << (8 * t);
    }
    whI[j*32 + kk] = wword;
  }
  dqs[j] = (amax / 16129.f) * ((g == 2) ? -2.885390082f : -1.442695041f);
}

// LDS: xgT[2] dbuf ([col][128 B of t] XOR-swizzled f16) + i8 h dbuf + f16 h.
// r13 structure (redundant in-lane nonlinearity, no cross-lane ops) with the
// lgkm-only step barrier (phase-A loads stay in flight across steps).
__global__ __launch_bounds__(512, 2)
void lstm_fused(
    const float* __restrict__ x, const u32* __restrict__ wxT,
    const u32* __restrict__ whI, const float* __restrict__ dqs,
    const float* __restrict__ w_out, float* __restrict__ out) {
  extern __shared__ char lds[];

  const int tid = threadIdx.x;
  const int b   = blockIdx.x;
  const int l   = tid & 63, wv = tid >> 6;
  const int kg  = l >> 4, r15 = l & 15;
  const int j   = wv * 16 + r15;   // hidden index this lane owns

  // i8 recurrence B-frags: bi8[g][m] = whI[(g*128+j)*32][m*16+kg*4 ..+4]
  uint4 bi8[4][2];
  float dqv[4];
#pragma unroll
  for (int g = 0; g < 4; ++g) {
    const uint4* wp = (const uint4*)(whI + (g * DH + j) * 32);
    bi8[g][0] = wp[kg];
    bi8[g][1] = wp[4 + kg];
    dqv[g] = dqs[g * DH + j];
  }
  // Phase-A B-frags (persistent, 64 VGPRs): this wave's 4 n-tiles
  uint4 bfA[4][4];
#pragma unroll
  for (int nt = 0; nt < 4; ++nt) {
    int n = wv * 64 + nt * 16 + r15;
#pragma unroll
    for (int ko = 0; ko < 4; ++ko)
      bfA[nt][ko] = *(const uint4*)(wxT + n*64 + ko*16 + kg*4);
  }

  if (tid < 64) ((u32*)(lds + HOFF))[tid] = 0u;   // zero both i8 h buffers
  float c = 0.f, lasth = 0.f;
  u32 rdh = HOFF;          // current h (i8[128])
  u32 wrh = HOFF + 128;    // next h
  const float* xb = x + (size_t)b * SEQL * DIN;
  const f32x4 Z  = {0.f, 0.f, 0.f, 0.f};
  const i32x4 ZI = {0, 0, 0, 0};
  __syncthreads();

  // ---- standalone phase A for chunk 0 -> buffer 0 ----
#pragma unroll 1
  for (int tt = 0; tt < 4; ++tt) {
    uint4 afr0[4];
#pragma unroll
    for (int ko = 0; ko < 4; ++ko) {
      const float4* xp = (const float4*)(xb + (size_t)(tt*16 + r15)*DIN + ko*32 + kg*8);
      float4 v0 = xp[0], v1 = xp[1];
      afr0[ko].x = pk2(v0.x, v0.y); afr0[ko].y = pk2(v0.z, v0.w);
      afr0[ko].z = pk2(v1.x, v1.y); afr0[ko].w = pk2(v1.z, v1.w);
    }
#pragma unroll
    for (int nt = 0; nt < 4; ++nt) {
      int n = wv * 64 + nt * 16 + r15;
      f32x4 acc = MF(afr0[0], bfA[nt][0], Z);
      acc = MF(afr0[1], bfA[nt][1], acc);
      acc = MF(afr0[2], bfA[nt][2], acc);
      acc = MF(afr0[3], bfA[nt][3], acc);
      int t0 = tt*16 + kg*4;
      u32 off = (u32)(n*128 + ((t0*2) ^ ((n & 7) << 4)));
      uint2 pw; pw.x = pk2(acc[0], acc[1]); pw.y = pk2(acc[2], acc[3]);
      *(uint2*)(lds + off) = pw;
    }
  }
  __syncthreads();

  int cur = 0;
#pragma unroll 1
  for (int ch = 0; ch < NCHUNK; ++ch) {
    char* xgC = lds + cur * 65536;
    char* xgN = lds + (cur ^ 1) * 65536;
    const bool doA = (ch + 1 < NCHUNK);
    float4 lv[8];    // staged x loads (issued even m, used even m s8>=2)
    uint4  afr[4];   // f16 A-frags   (built even m, consumed odd m)
    f32x4  aacc;     // A accumulator (odd m, spans 2 steps)

#pragma unroll 1
    for (int m = 0; m < 8; ++m) {
      const int tt = m >> 1;
      // xg for col j of each gate, timesteps [8m, 8m+8)  (pre-scaled)
      half8_t xh[4];
#pragma unroll
      for (int g = 0; g < 4; ++g) {
        int cg = g * DH + j;
        xh[g] = __builtin_bit_cast(half8_t,
            *(const uint4*)(xgC + cg*128 + ((m*16) ^ ((cg & 7) << 4))));
      }
#pragma unroll
      for (int s8 = 0; s8 < 8; ++s8) {
        // ---- interleaved phase A (chunk ch+1) ----
        if (doA) {
          if ((m & 1) == 0) {
            if (s8 == 0) {
              const float* xr = xb + (size_t)((ch+1)*TC + tt*16 + r15)*DIN + kg*8;
#pragma unroll
              for (int ko = 0; ko < 4; ++ko) {
                const float4* xp = (const float4*)(xr + ko*32);
                lv[2*ko]   = xp[0];
                lv[2*ko+1] = xp[1];
              }
            }
            if (s8 == 2) {
#pragma unroll
              for (int ko = 0; ko < 2; ++ko) {
                float4 v0 = lv[2*ko], v1 = lv[2*ko+1];
                afr[ko].x = pk2(v0.x, v0.y); afr[ko].y = pk2(v0.z, v0.w);
                afr[ko].z = pk2(v1.x, v1.y); afr[ko].w = pk2(v1.z, v1.w);
              }
            }
            if (s8 == 3) {
#pragma unroll
              for (int ko = 2; ko < 4; ++ko) {
                float4 v0 = lv[2*ko], v1 = lv[2*ko+1];
                afr[ko].x = pk2(v0.x, v0.y); afr[ko].y = pk2(v0.z, v0.w);
                afr[ko].z = pk2(v1.x, v1.y); afr[ko].w = pk2(v1.z, v1.w);
              }
            }
          } else {
            const int nt = s8 >> 1;      // compile-time (s8 unrolled)
            if ((s8 & 1) == 0) {
              aacc = MF(afr[1], bfA[nt][1], MF(afr[0], bfA[nt][0], Z));
            } else {
              aacc = MF(afr[3], bfA[nt][3], MF(afr[2], bfA[nt][2], aacc));
              int n = wv * 64 + nt * 16 + r15;
              int t0 = tt*16 + kg*4;
              u32 off = (u32)(n*128 + ((t0*2) ^ ((n & 7) << 4)));
              uint2 pw; pw.x = pk2(aacc[0], aacc[1]); pw.y = pk2(aacc[2], aacc[3]);
              *(uint2*)(xgN + off) = pw;
            }
          }
        }

        // ---- recurrence step (i8 gate GEMM, redundant in-lane nonlin) ----
        uint4 a0 = *(const uint4*)(lds + rdh + kg*16);        // k = kg*16+[0,16)
        uint4 a1 = *(const uint4*)(lds + rdh + 64 + kg*16);   // k = 64+kg*16+[0,16)
        i32x4 aci = MFI8(a0, bi8[0][0], ZI);
        i32x4 acf = MFI8(a0, bi8[1][0], ZI);
        i32x4 acg = MFI8(a0, bi8[2][0], ZI);
        i32x4 aco = MFI8(a0, bi8[3][0], ZI);
        aci = MFI8(a1, bi8[0][1], aci);
        acf = MFI8(a1, bi8[1][1], acf);
        acg = MFI8(a1, bi8[2][1], acg);
        aco = MFI8(a1, bi8[3][1], aco);
        // dequant (scale folds 1/127^2 and -log2e / -2log2e) + pre-scaled xg
        float gi = __builtin_fmaf((float)aci[0], dqv[0], (float)xh[0][s8]);
        float gf = __builtin_fmaf((float)acf[0], dqv[1], (float)xh[1][s8]);
        float gg = __builtin_fmaf((float)acg[0], dqv[2], (float)xh[2][s8]);
        float go = __builtin_fmaf((float)aco[0], dqv[3], (float)xh[3][s8]);
        float si = __builtin_amdgcn_rcpf(1.f + fexp2(gi));
        float sf = __builtin_amdgcn_rcpf(1.f + fexp2(gf));
        float sg = __builtin_fmaf(2.f, __builtin_amdgcn_rcpf(1.f + fexp2(gg)), -1.f);
        float so = __builtin_amdgcn_rcpf(1.f + fexp2(go));
        c = __builtin_fmaf(sf, c, si * sg);
        float th = __builtin_fmaf(2.f,
                     __builtin_amdgcn_rcpf(1.f + fexp2(c * -2.885390082f)), -1.f);
        float hval = so * th;
        lasth = hval;
        int q = (int)__builtin_rintf(hval * 127.f);   // h in (-1,1): no clamp
        if (l < 16) *(char*)(lds + wrh + j) = (char)q;
        u32 tswap = rdh; rdh = wrh; wrh = tswap;
        step_barrier();
      }
    }
    cur ^= 1;
  }

  // ---- publish exact final h as f16, then tail: out[b][n] = h @ w_out ----
  if (l < 16) *(__fp16*)(lds + HF2 + j * 2) = (__fp16)lasth;
  __syncthreads();
  if (tid < DH) {
    int n = tid;
    const u32* hf = (const u32*)(lds + HF2);   // final h (f16 pairs)
    float acc = 0.f;
#pragma unroll 8
    for (int kk = 0; kk < 64; ++kk) {
      half2_t h2v = __builtin_bit_cast(half2_t, hf[kk]);
      acc = __builtin_fmaf((float)h2v[0], w_out[(2*kk)*DH + n],
            __builtin_fmaf((float)h2v[1], w_out[(2*kk+1)*DH + n], acc));
    }
    out[b * DH + n] = acc;
  }
}

extern "C" void kernel_launch(void* const* d_in, const int* in_sizes, int n_in,
                              void* d_out, int out_size, void* d_ws, size_t ws_size,
                              hipStream_t stream) {
  const float* x    = (const float*)d_in[0];
  const float* x2i  = (const float*)d_in[1];
  const float* x2f  = (const float*)d_in[2];
  const float* x2g  = (const float*)d_in[3];
  const float* x2o  = (const float*)d_in[4];
  const float* h2i  = (const float*)d_in[5];
  const float* h2f  = (const float*)d_in[6];
  const float* h2g  = (const float*)d_in[7];
  const float* h2o  = (const float*)d_in[8];
  const float* wout = (const float*)d_in[9];

  u32*   wxT = (u32*)d_ws;                 // 32768 u32 = 128 KB
  u32*   whI = wxT + NC * 64;              // 16384 u32 =  64 KB
  float* dqs = (float*)(whI + NC * 32);    //   512 f32 =   2 KB

  (void)hipFuncSetAttribute((const void*)lstm_fused,
                            hipFuncAttributeMaxDynamicSharedMemorySize, LDS_TOTAL);

  pack_w<<<64, 512, 0, stream>>>(x2i, x2f, x2g, x2o, wxT);
  pack_whi8<<<1, 512, 0, stream>>>(h2i, h2f, h2g, h2o, whI, dqs);
  lstm_fused<<<NBATCH, 512, LDS_TOTAL, stream>>>(x, wxT, whI, dqs, wout, (float*)d_out);
}

// Round 19
// 255.553 us; speedup vs baseline: 1.6655x; 1.0181x over previous
//
#include <hip/hip_runtime.h>

typedef unsigned int u32;
typedef __fp16 half2_t __attribute__((ext_vector_type(2)));
typedef __fp16 half8_t __attribute__((ext_vector_type(8)));
typedef float  f32x4   __attribute__((ext_vector_type(4)));
typedef int    i32x4   __attribute__((ext_vector_type(4)));

#define DIN 128
#define DH  128
#define SEQL 512
#define NBATCH 256
#define NC  512          // 4*DH fused gate columns
#define TC  64           // timesteps per chunk
#define NCHUNK (SEQL/TC) // 8

#define HOFF 131072              // i8 h dbuf after 2 xgT buffers (2 x 128 B)
#define HF2  (131072 + 256)      // final f16 h for tail (256 B)
#define LDS_TOTAL (131072 + 256 + 256)

__device__ __forceinline__ u32 pk2(float a, float b) {
  half2_t h = __builtin_amdgcn_cvt_pkrtz(a, b);
  return __builtin_bit_cast(u32, h);
}

__device__ __forceinline__ float fexp2(float x) {
#if defined(__has_builtin) && __has_builtin(__builtin_amdgcn_exp2f)
  return __builtin_amdgcn_exp2f(x);
#else
  return __builtin_exp2f(x);
#endif
}

#define MF(A, B, C) __builtin_amdgcn_mfma_f32_16x16x32_f16( \
    __builtin_bit_cast(half8_t, A), __builtin_bit_cast(half8_t, B), C, 0, 0, 0)
#define MFI8(A, B, C) __builtin_amdgcn_mfma_i32_16x16x64_i8( \
    __builtin_bit_cast(i32x4, A), __builtin_bit_cast(i32x4, B), C, 0, 0, 0)

// Pack fused x-projection weights into f16-pair column-major image,
// PRE-SCALED by the exp2 conversion constants (i,f,o: -log2e; g: -2log2e).
__global__ void pack_w(const float* __restrict__ x2i, const float* __restrict__ x2f,
                       const float* __restrict__ x2g, const float* __restrict__ x2o,
                       u32* __restrict__ wxT) {
  int idx = blockIdx.x * blockDim.x + threadIdx.x;   // 0..32767
  if (idx >= NC * 64) return;
  int j = idx >> 6, kk = idx & 63;
  int g = j >> 7, jjj = j & 127;
  const float* wx = (g == 0) ? x2i : (g == 1) ? x2f : (g == 2) ? x2g : x2o;
  float s = (g == 2) ? -2.885390082f : -1.442695041f;
  wxT[idx] = pk2(s * wx[(2*kk)*DH + jjj], s * wx[(2*kk+1)*DH + jjj]);
}

// Quantize recurrence weights to i8, per-column scale; dequant scale folds
// 1/(127*127) and the exp2 gate constant.
__global__ void pack_whi8(const float* __restrict__ h2i, const float* __restrict__ h2f,
                          const float* __restrict__ h2g, const float* __restrict__ h2o,
                          u32* __restrict__ whI, float* __restrict__ dqs) {
  int j = blockIdx.x * blockDim.x + threadIdx.x;   // 0..511 fused col
  if (j >= NC) return;
  int g = j >> 7, jj = j & 127;
  const float* wh = (g == 0) ? h2i : (g == 1) ? h2f : (g == 2) ? h2g : h2o;
  float amax = 1e-20f;
  for (int k = 0; k < DH; ++k) amax = fmaxf(amax, fabsf(wh[k*DH + jj]));
  float s = 127.f / amax;
  for (int kk = 0; kk < 32; ++kk) {
    u32 wword = 0;
#pragma unroll
    for (int t = 0; t < 4; ++t) {
      int q = (int)__builtin_rintf(wh[(4*kk + t)*DH + jj] * s);
      wword |= ((u32)(q & 0xFF)) << (8 * t);
    }
    whI[j*32 + kk] = wword;
  }
  dqs[j] = (amax / 16129.f) * ((g == 2) ? -2.885390082f : -1.442695041f);
}

// LDS: xgT[2] dbuf ([col][128 B of t] XOR-swizzled f16) + i8 h dbuf + f16 h.
// Recurrence gate-GEMM on mfma_i32_16x16x64_i8 (K=64 -> 8 MFMA/wave/step);
// c and nonlinearity stay f32 in-register. Phase A (f16) interleaved.
__global__ __launch_bounds__(512, 2)
void lstm_fused(
    const float* __restrict__ x, const u32* __restrict__ wxT,
    const u32* __restrict__ whI, const float* __restrict__ dqs,
    const float* __restrict__ w_out, float* __restrict__ out) {
  extern __shared__ char lds[];

  const int tid = threadIdx.x;
  const int b   = blockIdx.x;
  const int l   = tid & 63, wv = tid >> 6;
  const int kg  = l >> 4, r15 = l & 15;
  const int j   = wv * 16 + r15;   // hidden index this lane owns

  // i8 recurrence B-frags: bi8[g][m] = whI[(g*128+j)*32][m*16+kg*4 ..+4]
  // (k = m*64 + kg*16 + [0,16))  -- 32 VGPRs
  uint4 bi8[4][2];
  float dqv[4];
#pragma unroll
  for (int g = 0; g < 4; ++g) {
    const uint4* wp = (const uint4*)(whI + (g * DH + j) * 32);
    bi8[g][0] = wp[kg];
    bi8[g][1] = wp[4 + kg];
    dqv[g] = dqs[g * DH + j];
  }
  // Phase-A B-frags (persistent, 64 VGPRs): this wave's 4 n-tiles
  uint4 bfA[4][4];
#pragma unroll
  for (int nt = 0; nt < 4; ++nt) {
    int n = wv * 64 + nt * 16 + r15;
#pragma unroll
    for (int ko = 0; ko < 4; ++ko)
      bfA[nt][ko] = *(const uint4*)(wxT + n*64 + ko*16 + kg*4);
  }

  if (tid < 64) ((u32*)(lds + HOFF))[tid] = 0u;   // zero both i8 h buffers
  float c = 0.f, lasth = 0.f;
  u32 rdh = HOFF;          // current h (i8[128])
  u32 wrh = HOFF + 128;    // next h
  const float* xb = x + (size_t)b * SEQL * DIN;
  const f32x4 Z  = {0.f, 0.f, 0.f, 0.f};
  const i32x4 ZI = {0, 0, 0, 0};
  __syncthreads();

  // ---- standalone phase A for chunk 0 -> buffer 0 ----
#pragma unroll 1
  for (int tt = 0; tt < 4; ++tt) {
    uint4 afr0[4];
#pragma unroll
    for (int ko = 0; ko < 4; ++ko) {
      const float4* xp = (const float4*)(xb + (size_t)(tt*16 + r15)*DIN + ko*32 + kg*8);
      float4 v0 = xp[0], v1 = xp[1];
      afr0[ko].x = pk2(v0.x, v0.y); afr0[ko].y = pk2(v0.z, v0.w);
      afr0[ko].z = pk2(v1.x, v1.y); afr0[ko].w = pk2(v1.z, v1.w);
    }
#pragma unroll
    for (int nt = 0; nt < 4; ++nt) {
      int n = wv * 64 + nt * 16 + r15;
      f32x4 acc = MF(afr0[0], bfA[nt][0], Z);
      acc = MF(afr0[1], bfA[nt][1], acc);
      acc = MF(afr0[2], bfA[nt][2], acc);
      acc = MF(afr0[3], bfA[nt][3], acc);
      int t0 = tt*16 + kg*4;
      u32 off = (u32)(n*128 + ((t0*2) ^ ((n & 7) << 4)));
      uint2 pw; pw.x = pk2(acc[0], acc[1]); pw.y = pk2(acc[2], acc[3]);
      *(uint2*)(lds + off) = pw;
    }
  }
  __syncthreads();

  int cur = 0;
#pragma unroll 1
  for (int ch = 0; ch < NCHUNK; ++ch) {
    char* xgC = lds + cur * 65536;
    char* xgN = lds + (cur ^ 1) * 65536;
    const bool doA = (ch + 1 < NCHUNK);
    float4 lv[8];    // staged x loads (even m)
    uint4  afr[4];   // f16 A-frags   (built even m, consumed odd m)
    f32x4  aacc;     // A accumulator (odd m, spans 2 steps)

#pragma unroll 1
    for (int m = 0; m < 8; ++m) {
      const int tt = m >> 1;
      // xg for col j of each gate, timesteps [8m, 8m+8)  (pre-scaled)
      half8_t xh[4];
#pragma unroll
      for (int g = 0; g < 4; ++g) {
        int cg = g * DH + j;
        xh[g] = __builtin_bit_cast(half8_t,
            *(const uint4*)(xgC + cg*128 + ((m*16) ^ ((cg & 7) << 4))));
      }
#pragma unroll
      for (int s8 = 0; s8 < 8; ++s8) {
        // ---- interleaved phase A (chunk ch+1) ----
        if (doA) {
          if ((m & 1) == 0) {
            if (s8 == 0) {
              const float* xr = xb + (size_t)((ch+1)*TC + tt*16 + r15)*DIN + kg*8;
#pragma unroll
              for (int ko = 0; ko < 4; ++ko) {
                const float4* xp = (const float4*)(xr + ko*32);
                lv[2*ko]   = xp[0];
                lv[2*ko+1] = xp[1];
              }
            }
            if (s8 == 2) {
#pragma unroll
              for (int ko = 0; ko < 2; ++ko) {
                float4 v0 = lv[2*ko], v1 = lv[2*ko+1];
                afr[ko].x = pk2(v0.x, v0.y); afr[ko].y = pk2(v0.z, v0.w);
                afr[ko].z = pk2(v1.x, v1.y); afr[ko].w = pk2(v1.z, v1.w);
              }
            }
            if (s8 == 3) {
#pragma unroll
              for (int ko = 2; ko < 4; ++ko) {
                float4 v0 = lv[2*ko], v1 = lv[2*ko+1];
                afr[ko].x = pk2(v0.x, v0.y); afr[ko].y = pk2(v0.z, v0.w);
                afr[ko].z = pk2(v1.x, v1.y); afr[ko].w = pk2(v1.z, v1.w);
              }
            }
          } else {
            const int nt = s8 >> 1;      // compile-time (s8 unrolled)
            if ((s8 & 1) == 0) {
              aacc = MF(afr[1], bfA[nt][1], MF(afr[0], bfA[nt][0], Z));
            } else {
              aacc = MF(afr[3], bfA[nt][3], MF(afr[2], bfA[nt][2], aacc));
              int n = wv * 64 + nt * 16 + r15;
              int t0 = tt*16 + kg*4;
              u32 off = (u32)(n*128 + ((t0*2) ^ ((n & 7) << 4)));
              uint2 pw; pw.x = pk2(aacc[0], aacc[1]); pw.y = pk2(aacc[2], aacc[3]);
              *(uint2*)(xgN + off) = pw;
            }
          }
        }

        // ---- recurrence step (i8 gate GEMM) ----
        uint4 a0 = *(const uint4*)(lds + rdh + kg*16);        // k = kg*16+[0,16)
        uint4 a1 = *(const uint4*)(lds + rdh + 64 + kg*16);   // k = 64+kg*16+[0,16)
        i32x4 aci = MFI8(a0, bi8[0][0], ZI);
        i32x4 acf = MFI8(a0, bi8[1][0], ZI);
        i32x4 acg = MFI8(a0, bi8[2][0], ZI);
        i32x4 aco = MFI8(a0, bi8[3][0], ZI);
        aci = MFI8(a1, bi8[0][1], aci);
        acf = MFI8(a1, bi8[1][1], acf);
        acg = MFI8(a1, bi8[2][1], acg);
        aco = MFI8(a1, bi8[3][1], aco);
        // dequant (scale folds 1/127^2 and -log2e / -2log2e) + pre-scaled xg
        float gi = __builtin_fmaf((float)aci[0], dqv[0], (float)xh[0][s8]);
        float gf = __builtin_fmaf((float)acf[0], dqv[1], (float)xh[1][s8]);
        float gg = __builtin_fmaf((float)acg[0], dqv[2], (float)xh[2][s8]);
        float go = __builtin_fmaf((float)aco[0], dqv[3], (float)xh[3][s8]);
        float si = __builtin_amdgcn_rcpf(1.f + fexp2(gi));
        float sf = __builtin_amdgcn_rcpf(1.f + fexp2(gf));
        float sg = __builtin_fmaf(2.f, __builtin_amdgcn_rcpf(1.f + fexp2(gg)), -1.f);
        float so = __builtin_amdgcn_rcpf(1.f + fexp2(go));
        c = __builtin_fmaf(sf, c, si * sg);
        float th = __builtin_fmaf(2.f,
                     __builtin_amdgcn_rcpf(1.f + fexp2(c * -2.885390082f)), -1.f);
        float hval = so * th;
        lasth = hval;
        int q = (int)__builtin_rintf(hval * 127.f);   // h in (-1,1): no clamp
        if (l < 16) *(char*)(lds + wrh + j) = (char)q;
        u32 tswap = rdh; rdh = wrh; wrh = tswap;
        __syncthreads();
      }
    }
    cur ^= 1;
  }

  // ---- publish exact final h as f16, then tail: out[b][n] = h @ w_out ----
  if (l < 16) *(__fp16*)(lds + HF2 + j * 2) = (__fp16)lasth;
  __syncthreads();
  if (tid < DH) {
    int n = tid;
    const u32* hf = (const u32*)(lds + HF2);   // final h (f16 pairs)
    float acc = 0.f;
#pragma unroll 8
    for (int kk = 0; kk < 64; ++kk) {
      half2_t h2v = __builtin_bit_cast(half2_t, hf[kk]);
      acc = __builtin_fmaf((float)h2v[0], w_out[(2*kk)*DH + n],
            __builtin_fmaf((float)h2v[1], w_out[(2*kk+1)*DH + n], acc));
    }
    out[b * DH + n] = acc;
  }
}

extern "C" void kernel_launch(void* const* d_in, const int* in_sizes, int n_in,
                              void* d_out, int out_size, void* d_ws, size_t ws_size,
                              hipStream_t stream) {
  const float* x    = (const float*)d_in[0];
  const float* x2i  = (const float*)d_in[1];
  const float* x2f  = (const float*)d_in[2];
  const float* x2g  = (const float*)d_in[3];
  const float* x2o  = (const float*)d_in[4];
  const float* h2i  = (const float*)d_in[5];
  const float* h2f  = (const float*)d_in[6];
  const float* h2g  = (const float*)d_in[7];
  const float* h2o  = (const float*)d_in[8];
  const float* wout = (const float*)d_in[9];

  u32*   wxT = (u32*)d_ws;                 // 32768 u32 = 128 KB
  u32*   whI = wxT + NC * 64;              // 16384 u32 =  64 KB
  float* dqs = (float*)(whI + NC * 32);    //   512 f32 =   2 KB

  (void)hipFuncSetAttribute((const void*)lstm_fused,
                            hipFuncAttributeMaxDynamicSharedMemorySize, LDS_TOTAL);

  pack_w<<<64, 512, 0, stream>>>(x2i, x2f, x2g, x2o, wxT);
  pack_whi8<<<1, 512, 0, stream>>>(h2i, h2f, h2g, h2o, whI, dqs);
  lstm_fused<<<NBATCH, 512, LDS_TOTAL, stream>>>(x, wxT, whI, dqs, wout, (float*)d_out);
}